// Round 6
// baseline (2319.105 us; speedup 1.0000x reference)
//
#include <hip/hip_runtime.h>

#define NN 512
#define BB 64
#define TT 1000

typedef unsigned int u32;
typedef _Float16 h2_t __attribute__((ext_vector_type(2)));

// acc += s[0]*w[0] + s[1]*w[1]  (f16 inputs, f32 accumulate) — v_dot2_f32_f16
__device__ inline float fdot2(u32 su, u32 wu, float acc) {
#if __has_builtin(__builtin_amdgcn_fdot2)
    return __builtin_amdgcn_fdot2(__builtin_bit_cast(h2_t, su),
                                  __builtin_bit_cast(h2_t, wu), acc, false);
#else
    h2_t s = __builtin_bit_cast(h2_t, su);
    h2_t w = __builtin_bit_cast(h2_t, wu);
    return fmaf((float)s[0], (float)w[0], fmaf((float)s[1], (float)w[1], acc));
#endif
}

// ---------------------------------------------------------------------------
// Pack W[n][k] (f32) -> Wp[kp][n] (u32 = half2(W[n][2kp], W[n][2kp+1])).
// ---------------------------------------------------------------------------
__global__ __launch_bounds__(256) void pack_w(const float* __restrict__ W,
                                              u32* __restrict__ Wp) {
    const int n = blockIdx.x;      // 0..511
    const int j = threadIdx.x;     // kp 0..255
    const float2 w = reinterpret_cast<const float2*>(W + (size_t)n * NN)[j];
    h2_t h;
    h[0] = (_Float16)w.x;
    h[1] = (_Float16)w.y;
    Wp[(size_t)j * NN + n] = __builtin_bit_cast(u32, h);
}

// ---------------------------------------------------------------------------
// Persistent scan, W fully CU-resident: one WG per batch, 512 threads
// (8 waves, 2/SIMD; occupancy LDS-capped at 1 WG/CU, 137 KB).
// Thread (ks=tid>>7, c=tid&127) owns k in [ks*128, ks*128+128) x cols
// {4c..4c+3}:
//   - kp-local rows 0..47: 192 dwords/thread staged into AGPRs via explicit
//     v_accvgpr_write_b32 (rounds 3-5: the allocator refuses to keep them in
//     arch VGPRs — sinks the loads (r3) or shuffles via hidden copies (r4/r5)).
//     Reads back with v_accvgpr_read_b32 per use; volatile asm prevents LICM
//     from hoisting 192 live values out of the T-loop.
//   - kp-local rows 48..63: LDS (128 KB), loaded once.
// Per step: tanh->LDS(f16) | bar | 256 dot2 (+192 accvgpr_read) | part write
// | bar | 4-way k-reduce + state update + store. Zero W memory traffic.
// ---------------------------------------------------------------------------
__global__ __launch_bounds__(512)
__attribute__((amdgpu_waves_per_eu(2, 2)))
void rnn_scan(const float* __restrict__ h0v,
              const float* __restrict__ X,
              const u32* __restrict__ Wp,
              float* __restrict__ hid) {
    const int b = blockIdx.x;
    const int tid = threadIdx.x;     // tid == owned hidden index n
    const int c = tid & 127;
    const int ks = tid >> 7;

    __shared__ __attribute__((aligned(16))) unsigned short th_h[NN];   // 1 KB
    __shared__ uint4 wlds[4 * 16 * 128];                                // 128 KB
    __shared__ float4 part4[4][128];                                    // 8 KB

    const uint4* wp4 = reinterpret_cast<const uint4*>(Wp);  // rows of 128 uint4

    // ---- prologue: stage 48 uint4 (192 dwords) into AGPRs, chunked so the
    // prologue never holds more than 8 uint4 (32 arch VGPRs) in flight ----
    u32 wa[192];   // every access statically indexed -> SSA, AGPR class
#pragma unroll
    for (int jc = 0; jc < 6; ++jc) {
#pragma unroll
        for (int j8 = 0; j8 < 8; ++j8) {
            const int j = jc * 8 + j8;
            const uint4 v = wp4[(size_t)(ks * 64 + j) * 128 + c];
            asm volatile("v_accvgpr_write_b32 %0, %1" : "=a"(wa[4 * j + 0]) : "v"(v.x));
            asm volatile("v_accvgpr_write_b32 %0, %1" : "=a"(wa[4 * j + 1]) : "v"(v.y));
            asm volatile("v_accvgpr_write_b32 %0, %1" : "=a"(wa[4 * j + 2]) : "v"(v.z));
            asm volatile("v_accvgpr_write_b32 %0, %1" : "=a"(wa[4 * j + 3]) : "v"(v.w));
        }
        __builtin_amdgcn_sched_barrier(0);
    }

    // ---- rows 48..63 into LDS ----
#pragma unroll
    for (int j = 0; j < 16; ++j)
        wlds[(ks * 16 + j) * 128 + c] = wp4[(size_t)(ks * 64 + 48 + j) * 128 + c];

    const float* xb = X + (size_t)b * TT * NN;
    float h = h0v[tid];
    float xn = xb[tid];
    __syncthreads();

    const uint4* thv = reinterpret_cast<const uint4*>(th_h);
    const float* pf = reinterpret_cast<const float*>(part4);  // pf[ks*512 + n]
    const uint4* wl = &wlds[ks * 16 * 128 + c];                // + j*128

    for (int t = 0; t < TT; ++t) {
        {
            const _Float16 hh = (_Float16)tanhf(h);
            th_h[tid] = __builtin_bit_cast(unsigned short, hh);
        }
        __syncthreads();

        // Prefetch next x (HBM/L3 latency hides under the matvec).
        float xnext = (t + 1 < TT) ? xb[(size_t)(t + 1) * NN + tid] : 0.f;

        float a0 = 0.f, a1 = 0.f, a2 = 0.f, a3 = 0.f;
        // --- AGPR-resident W: kp rows 0..47 (q = group of 4 kp = 8 k) ---
#pragma unroll
        for (int q = 0; q < 12; ++q) {
            const uint4 s = thv[ks * 16 + q];   // same addr across wave: broadcast
#pragma unroll
            for (int r = 0; r < 4; ++r) {        // kp row 4q+r, s component r
                const u32 sr = (r == 0) ? s.x : (r == 1) ? s.y : (r == 2) ? s.z : s.w;
                u32 w0, w1, w2, w3;
                asm volatile("v_accvgpr_read_b32 %0, %1" : "=v"(w0) : "a"(wa[16 * q + 4 * r + 0]));
                asm volatile("v_accvgpr_read_b32 %0, %1" : "=v"(w1) : "a"(wa[16 * q + 4 * r + 1]));
                asm volatile("v_accvgpr_read_b32 %0, %1" : "=v"(w2) : "a"(wa[16 * q + 4 * r + 2]));
                asm volatile("v_accvgpr_read_b32 %0, %1" : "=v"(w3) : "a"(wa[16 * q + 4 * r + 3]));
                a0 = fdot2(sr, w0, a0);
                a1 = fdot2(sr, w1, a1);
                a2 = fdot2(sr, w2, a2);
                a3 = fdot2(sr, w3, a3);
            }
        }
        // --- LDS-resident W: kp rows 48..63 ---
#pragma unroll
        for (int q = 0; q < 4; ++q) {
            const uint4 s = thv[ks * 16 + 12 + q];
            const uint4 w0 = wl[(4 * q + 0) * 128];
            const uint4 w1 = wl[(4 * q + 1) * 128];
            const uint4 w2 = wl[(4 * q + 2) * 128];
            const uint4 w3 = wl[(4 * q + 3) * 128];
            a0 = fdot2(s.x, w0.x, a0); a1 = fdot2(s.x, w0.y, a1);
            a2 = fdot2(s.x, w0.z, a2); a3 = fdot2(s.x, w0.w, a3);
            a0 = fdot2(s.y, w1.x, a0); a1 = fdot2(s.y, w1.y, a1);
            a2 = fdot2(s.y, w1.z, a2); a3 = fdot2(s.y, w1.w, a3);
            a0 = fdot2(s.z, w2.x, a0); a1 = fdot2(s.z, w2.y, a1);
            a2 = fdot2(s.z, w2.z, a2); a3 = fdot2(s.z, w2.w, a3);
            a0 = fdot2(s.w, w3.x, a0); a1 = fdot2(s.w, w3.y, a1);
            a2 = fdot2(s.w, w3.z, a2); a3 = fdot2(s.w, w3.w, a3);
        }
        part4[ks][c] = make_float4(a0, a1, a2, a3);
        __syncthreads();

        // k-reduce for n = tid: pf[ks*512 + n], ks = 0..3
        const float s = (pf[tid] + pf[512 + tid]) + (pf[1024 + tid] + pf[1536 + tid]);
        h = 0.9f * h + 0.1f * (s + xn);
        hid[((size_t)t * BB + b) * NN + tid] = h;
        xn = xnext;
        // No third barrier: next phase writes th_h (guarded by bar1 before the
        // reads), and part4 is rewritten only after bar1.
    }
}

// ---------------------------------------------------------------------------
// geometry = tanh(hidden_t) @ G_w.T + G_b ; readout = geometry @ D.T
// ---------------------------------------------------------------------------
__global__ __launch_bounds__(256) void geo_read(const float* __restrict__ hid,
                                                const float* __restrict__ Gw,
                                                const float* __restrict__ Gb,
                                                float* __restrict__ geo,
                                                float* __restrict__ rdo) {
    const int wave = (int)((blockIdx.x * 256 + threadIdx.x) >> 6);  // 0..63999
    const int lane = threadIdx.x & 63;
    if (wave >= TT * BB) return;

    const float* hrow = hid + (size_t)wave * NN;
    float g0 = 0.f, g1 = 0.f;
#pragma unroll
    for (int i = 0; i < 2; ++i) {
        const int off = i * 256 + lane * 4;
        const float4 hv = *reinterpret_cast<const float4*>(hrow + off);
        const float4 w0 = *reinterpret_cast<const float4*>(Gw + off);
        const float4 w1 = *reinterpret_cast<const float4*>(Gw + NN + off);
        const float t0 = tanhf(hv.x), t1 = tanhf(hv.y), t2 = tanhf(hv.z), t3 = tanhf(hv.w);
        g0 = fmaf(t0, w0.x, fmaf(t1, w0.y, fmaf(t2, w0.z, fmaf(t3, w0.w, g0))));
        g1 = fmaf(t0, w1.x, fmaf(t1, w1.y, fmaf(t2, w1.z, fmaf(t3, w1.w, g1))));
    }
#pragma unroll
    for (int off = 32; off > 0; off >>= 1) {
        g0 += __shfl_down(g0, off);
        g1 += __shfl_down(g1, off);
    }
    if (lane == 0) {
        g0 += Gb[0];
        g1 += Gb[1];
        geo[(size_t)wave * 2 + 0] = g0;
        geo[(size_t)wave * 2 + 1] = g1;
        const float dc[6] = {1.0f, 0.5f, -0.5f, -1.0f, -0.5f, 0.5f};
        const float ds[6] = {0.0f, 0.86602540378443865f, 0.86602540378443871f,
                             1.2246467991473532e-16f, -0.86602540378443837f,
                             -0.86602540378443860f};
#pragma unroll
        for (int k = 0; k < 6; ++k)
            rdo[(size_t)wave * 6 + k] = fmaf(g0, dc[k], g1 * ds[k]);
    }
}

extern "C" void kernel_launch(void* const* d_in, const int* in_sizes, int n_in,
                              void* d_out, int out_size, void* d_ws, size_t ws_size,
                              hipStream_t stream) {
    const float* h0 = (const float*)d_in[0];   // [512]
    const float* X  = (const float*)d_in[1];   // [64,1000,512]
    const float* W  = (const float*)d_in[2];   // [512,512]
    const float* Gw = (const float*)d_in[3];   // [2,512]
    const float* Gb = (const float*)d_in[4];   // [2]

    float* out = (float*)d_out;
    float* hid = out;                                   // [T*B*N]
    float* geo = out + (size_t)TT * BB * NN;            // [T*B*2]
    float* rdo = geo + (size_t)TT * BB * 2;             // [T*B*6]

    // Packed f16 W: 512 KB. Fallback: geo+rdo region (2 MB, overwritten later).
    const size_t wp_bytes = (size_t)NN * NN * sizeof(unsigned short);
    u32* Wp = (ws_size >= wp_bytes) ? (u32*)d_ws : (u32*)geo;

    pack_w<<<NN, 256, 0, stream>>>(W, Wp);
    rnn_scan<<<BB, 512, 0, stream>>>(h0, X, Wp, hid);
    geo_read<<<(TT * BB) / 4, 256, 0, stream>>>(hid, Gw, Gb, geo, rdo);
}

// Round 7
// 1804.042 us; speedup vs baseline: 1.2855x; 1.2855x over previous
//
#include <hip/hip_runtime.h>

#define NN 512
#define BB 64
#define TT 1000

typedef unsigned int u32;
typedef _Float16 h2_t __attribute__((ext_vector_type(2)));

// acc += s[0]*w[0] + s[1]*w[1]  (f16 inputs, f32 accumulate) — v_dot2_f32_f16
__device__ inline float fdot2(u32 su, u32 wu, float acc) {
#if __has_builtin(__builtin_amdgcn_fdot2)
    return __builtin_amdgcn_fdot2(__builtin_bit_cast(h2_t, su),
                                  __builtin_bit_cast(h2_t, wu), acc, false);
#else
    h2_t s = __builtin_bit_cast(h2_t, su);
    h2_t w = __builtin_bit_cast(h2_t, wu);
    return fmaf((float)s[0], (float)w[0], fmaf((float)s[1], (float)w[1], acc));
#endif
}

__device__ inline u32 h2pack(float a, float b) {
    h2_t h;
    h[0] = (_Float16)a;
    h[1] = (_Float16)b;
    return __builtin_bit_cast(u32, h);
}

// ---------------------------------------------------------------------------
// Pack W[n][k] f32 -> wpk[(ks*32+jj)*256 + c] uint4, where kp = ks*64+2*jj:
//   .x = h2(W[2c  ][2kp],   W[2c  ][2kp+1])   (kp row,   col 2c)
//   .y = h2(W[2c+1][2kp],   W[2c+1][2kp+1])   (kp row,   col 2c+1)
//   .z = h2(W[2c  ][2kp+2], W[2c  ][2kp+3])   (kp+1 row, col 2c)
//   .w = h2(W[2c+1][2kp+2], W[2c+1][2kp+3])   (kp+1 row, col 2c+1)
// One-time 1 MB repack; uncoalesced reads are fine.
// ---------------------------------------------------------------------------
__global__ __launch_bounds__(256) void pack_w(const float* __restrict__ W,
                                              uint4* __restrict__ wpk) {
    const int c = threadIdx.x;                       // 0..255
    const int blk = blockIdx.x;                      // 0..127 = ks*32+jj
    const int kp = (blk >> 5) * 64 + (blk & 31) * 2; // k-pair index
    const int k0 = 2 * kp;
    const float* r0 = W + (size_t)(2 * c) * NN + k0;
    const float* r1 = W + (size_t)(2 * c + 1) * NN + k0;
    uint4 v;
    v.x = h2pack(r0[0], r0[1]);
    v.y = h2pack(r1[0], r1[1]);
    v.z = h2pack(r0[2], r0[3]);
    v.w = h2pack(r1[2], r1[3]);
    wpk[(size_t)blk * 256 + c] = v;
}

// ---------------------------------------------------------------------------
// Persistent scan: one WG per batch, 1024 threads (16 waves, 4/SIMD; LDS caps
// occupancy at 1 WG/CU so 4/SIMD is free latency hiding). Thread (ks=tid>>8,
// c=tid&255) owns k in [128ks,128ks+128) x cols {2c,2c+1} = 128 W-dwords:
//   jj  0..15 -> 16 uint4 in VGPRs (64 dw; 64+~50 working fits the
//                allocator's observed 128-VGPR posture — rounds 3-6 showed
//                192 dw/thread gets sunk (r3), spilled (r4/5), or
//                serialized via volatile AGPR asm (r6))
//   jj 16..23 -> LDS-resident, 128 KB/CU, ~1540 cy/step on the LDS pipe
//   jj 24..31 -> streamed from L2, 128 KB/step/CU, ~1200 cy on the VMEM pipe
// The three sources drain three different pipes and overlap.
// Per step: tanh->LDS(f16) | bar | 128 dot2/thread | part | bar | k-reduce.
// ---------------------------------------------------------------------------
#define DOT8(s, wA, wB)                                          \
    a0 = fdot2((s).x, (wA).x, a0); a1 = fdot2((s).x, (wA).y, a1); \
    a0 = fdot2((s).y, (wA).z, a0); a1 = fdot2((s).y, (wA).w, a1); \
    a0 = fdot2((s).z, (wB).x, a0); a1 = fdot2((s).z, (wB).y, a1); \
    a0 = fdot2((s).w, (wB).z, a0); a1 = fdot2((s).w, (wB).w, a1);

__global__ __launch_bounds__(1024)
__attribute__((amdgpu_waves_per_eu(4, 4)))
void rnn_scan(const float* __restrict__ h0v,
              const float* __restrict__ X,
              const uint4* __restrict__ wpk,
              float* __restrict__ hid) {
    const int b = blockIdx.x;
    const int tid = threadIdx.x;   // tid<512: owns hidden element n=tid
    const int c = tid & 255;
    const int ks = tid >> 8;       // constant within each wave

    __shared__ __attribute__((aligned(16))) unsigned short th_h[NN];  // 1 KB
    __shared__ uint4 wlds[4 * 8 * 256];                                // 128 KB
    __shared__ float2 part[4][256];                                    // 8 KB

    // ---- prologue: VGPR-resident W (jj 0..15), pinned non-volatile ----
    uint4 wreg[16];
#pragma unroll
    for (int j = 0; j < 16; ++j)
        wreg[j] = wpk[(size_t)(ks * 32 + j) * 256 + c];
#pragma unroll
    for (int j = 0; j < 16; ++j)
        asm("" : "+v"(wreg[j].x), "+v"(wreg[j].y), "+v"(wreg[j].z), "+v"(wreg[j].w));
    // ---- LDS-resident W (jj 16..23) ----
#pragma unroll
    for (int j = 0; j < 8; ++j)
        wlds[(ks * 8 + j) * 256 + c] = wpk[(size_t)(ks * 32 + 16 + j) * 256 + c];

    const float* xb = X + (size_t)b * TT * NN;
    float h = 0.f, xn = 0.f;
    if (tid < NN) {
        h = h0v[tid];
        xn = xb[tid];
    }
    __syncthreads();

    const uint4* thv = reinterpret_cast<const uint4*>(th_h);  // [ks*16+p]: wave-uniform
    const float* pf = reinterpret_cast<const float*>(part);   // pf[ks*512 + n]
    const uint4* wl  = wlds + ks * 8 * 256 + c;               // + q*256
    const uint4* wsA = wpk + (size_t)(ks * 32 + 24) * 256 + c; // jj 24..27
    const uint4* wsB = wpk + (size_t)(ks * 32 + 28) * 256 + c; // jj 28..31

    for (int t = 0; t < TT; ++t) {
        if (tid < NN) {
            const _Float16 hh = (_Float16)tanhf(h);
            th_h[tid] = __builtin_bit_cast(unsigned short, hh);
        }
        __syncthreads();

        // x prefetch (HBM/L3 latency hides under the matvec)
        float xnext = (tid < NN && t + 1 < TT) ? xb[(size_t)(t + 1) * NN + tid] : 0.f;

        // issue stream group A early (4 uint4 = 16 regs in flight)
        const uint4 vA0 = wsA[0 * 256], vA1 = wsA[1 * 256],
                    vA2 = wsA[2 * 256], vA3 = wsA[3 * 256];

        float a0 = 0.f, a1 = 0.f;
        // --- VGPR W: p = 0..7 (jj = 2p, 2p+1) ---
#pragma unroll
        for (int p = 0; p < 8; ++p) {
            const uint4 s = thv[ks * 16 + p];    // broadcast (wave-uniform addr)
            DOT8(s, wreg[2 * p], wreg[2 * p + 1]);
        }
        // issue stream group B
        const uint4 vB0 = wsB[0 * 256], vB1 = wsB[1 * 256],
                    vB2 = wsB[2 * 256], vB3 = wsB[3 * 256];
        // --- LDS W: p = 8..11 ---
#pragma unroll
        for (int p = 0; p < 4; ++p) {
            const uint4 s = thv[ks * 16 + 8 + p];
            const uint4 wA = wl[(2 * p) * 256];
            const uint4 wB = wl[(2 * p + 1) * 256];
            DOT8(s, wA, wB);
        }
        // --- streamed W: p = 12..15 ---
        {
            const uint4 s12 = thv[ks * 16 + 12];
            DOT8(s12, vA0, vA1);
            const uint4 s13 = thv[ks * 16 + 13];
            DOT8(s13, vA2, vA3);
            const uint4 s14 = thv[ks * 16 + 14];
            DOT8(s14, vB0, vB1);
            const uint4 s15 = thv[ks * 16 + 15];
            DOT8(s15, vB2, vB3);
        }
        part[ks][c] = make_float2(a0, a1);
        __syncthreads();

        if (tid < NN) {
            const float sum = (pf[tid] + pf[512 + tid]) + (pf[1024 + tid] + pf[1536 + tid]);
            h = 0.9f * h + 0.1f * (sum + xn);
            hid[((size_t)t * BB + b) * NN + tid] = h;
            xn = xnext;
        }
        // 2-barrier scheme: next th_h write is fenced by bar1; part rewrite by
        // data-dependence of ds_write on all dot2s (which consumed thv reads).
    }
}

// ---------------------------------------------------------------------------
// geometry = tanh(hidden_t) @ G_w.T + G_b ; readout = geometry @ D.T
// ---------------------------------------------------------------------------
__global__ __launch_bounds__(256) void geo_read(const float* __restrict__ hid,
                                                const float* __restrict__ Gw,
                                                const float* __restrict__ Gb,
                                                float* __restrict__ geo,
                                                float* __restrict__ rdo) {
    const int wave = (int)((blockIdx.x * 256 + threadIdx.x) >> 6);  // 0..63999
    const int lane = threadIdx.x & 63;
    if (wave >= TT * BB) return;

    const float* hrow = hid + (size_t)wave * NN;
    float g0 = 0.f, g1 = 0.f;
#pragma unroll
    for (int i = 0; i < 2; ++i) {
        const int off = i * 256 + lane * 4;
        const float4 hv = *reinterpret_cast<const float4*>(hrow + off);
        const float4 w0 = *reinterpret_cast<const float4*>(Gw + off);
        const float4 w1 = *reinterpret_cast<const float4*>(Gw + NN + off);
        const float t0 = tanhf(hv.x), t1 = tanhf(hv.y), t2 = tanhf(hv.z), t3 = tanhf(hv.w);
        g0 = fmaf(t0, w0.x, fmaf(t1, w0.y, fmaf(t2, w0.z, fmaf(t3, w0.w, g0))));
        g1 = fmaf(t0, w1.x, fmaf(t1, w1.y, fmaf(t2, w1.z, fmaf(t3, w1.w, g1))));
    }
#pragma unroll
    for (int off = 32; off > 0; off >>= 1) {
        g0 += __shfl_down(g0, off);
        g1 += __shfl_down(g1, off);
    }
    if (lane == 0) {
        g0 += Gb[0];
        g1 += Gb[1];
        geo[(size_t)wave * 2 + 0] = g0;
        geo[(size_t)wave * 2 + 1] = g1;
        const float dc[6] = {1.0f, 0.5f, -0.5f, -1.0f, -0.5f, 0.5f};
        const float ds[6] = {0.0f, 0.86602540378443865f, 0.86602540378443871f,
                             1.2246467991473532e-16f, -0.86602540378443837f,
                             -0.86602540378443860f};
#pragma unroll
        for (int k = 0; k < 6; ++k)
            rdo[(size_t)wave * 6 + k] = fmaf(g0, dc[k], g1 * ds[k]);
    }
}

extern "C" void kernel_launch(void* const* d_in, const int* in_sizes, int n_in,
                              void* d_out, int out_size, void* d_ws, size_t ws_size,
                              hipStream_t stream) {
    const float* h0 = (const float*)d_in[0];   // [512]
    const float* X  = (const float*)d_in[1];   // [64,1000,512]
    const float* W  = (const float*)d_in[2];   // [512,512]
    const float* Gw = (const float*)d_in[3];   // [2,512]
    const float* Gb = (const float*)d_in[4];   // [2]

    float* out = (float*)d_out;
    float* hid = out;                                   // [T*B*N]
    float* geo = out + (size_t)TT * BB * NN;            // [T*B*2]
    float* rdo = geo + (size_t)TT * BB * 2;             // [T*B*6]

    // Packed f16 W: 512 KB. Fallback: geo+rdo region (2 MB, overwritten later).
    const size_t wp_bytes = (size_t)NN * NN * sizeof(unsigned short);
    uint4* Wpk = (ws_size >= wp_bytes) ? (uint4*)d_ws : (uint4*)geo;

    pack_w<<<128, 256, 0, stream>>>(W, Wpk);
    rnn_scan<<<BB, 1024, 0, stream>>>(h0, X, Wpk, hid);
    geo_read<<<(TT * BB) / 4, 256, 0, stream>>>(hid, Gw, Gb, geo, rdo);
}